// Round 1
// baseline (2132.288 us; speedup 1.0000x reference)
//
#include <hip/hip_runtime.h>

#define NN 100000

// ---------------- zero fill (float4 grid-stride) ----------------
__global__ void zero_kernel(float* __restrict__ p, long n4) {
    long i = (long)blockIdx.x * blockDim.x + threadIdx.x;
    long stride = (long)gridDim.x * blockDim.x;
    for (long j = i; j < n4; j += stride) {
        reinterpret_cast<float4*>(p)[j] = make_float4(0.f, 0.f, 0.f, 0.f);
    }
}

// ---------------- degree via atomics ----------------
__global__ void deg_kernel(const int* __restrict__ dst, float* __restrict__ deg, int E) {
    int e = blockIdx.x * blockDim.x + threadIdx.x;
    if (e < E) atomicAdd(&deg[dst[e]], 1.0f);
}

// ---------------- GEMM: C[N,COUT] = X[N,CIN] @ W[COUT,CIN]^T ----------------
template <int CIN, int COUT>
__global__ __launch_bounds__(1024) void gemm_kernel(
    const float* __restrict__ X, const float* __restrict__ W,
    float* __restrict__ C, int N)
{
    constexpr int COLG = COUT / 4;          // float4 column groups
    constexpr int ROWS = (1024 / COLG) * 2; // rows per block (2 per thread)
    __shared__ float wt[CIN * COUT];        // wt[k*COUT + c] = W[c*CIN + k]
    __shared__ float xs[ROWS * CIN];

    const int tid = threadIdx.x;
    // Load W transposed into LDS (global reads strided but W is 32-64KB, cached)
    for (int i = tid; i < CIN * COUT; i += 1024) {
        int c = i % COUT, k = i / COUT;
        wt[k * COUT + c] = W[c * CIN + k];
    }
    // Load X tile (coalesced float4)
    const int row0 = blockIdx.x * ROWS;
    for (int i = tid * 4; i < ROWS * CIN; i += 1024 * 4) {
        int r = i / CIN;
        int gr = row0 + r;
        float4 v = make_float4(0.f, 0.f, 0.f, 0.f);
        if (gr < N) v = *reinterpret_cast<const float4*>(&X[(size_t)gr * CIN + (i % CIN)]);
        *reinterpret_cast<float4*>(&xs[i]) = v;
    }
    __syncthreads();

    const int cg = tid % COLG;
    const int rs = tid / COLG;
    const int r0 = rs * 2, r1 = r0 + 1;
    const float* __restrict__ xp0 = &xs[r0 * CIN];
    const float* __restrict__ xp1 = &xs[r1 * CIN];

    float4 a0 = make_float4(0.f, 0.f, 0.f, 0.f);
    float4 a1 = make_float4(0.f, 0.f, 0.f, 0.f);
#pragma unroll 4
    for (int k = 0; k < CIN; ++k) {
        float4 w = *reinterpret_cast<const float4*>(&wt[k * COUT + cg * 4]);
        float v0 = xp0[k], v1 = xp1[k];
        a0.x = fmaf(v0, w.x, a0.x); a0.y = fmaf(v0, w.y, a0.y);
        a0.z = fmaf(v0, w.z, a0.z); a0.w = fmaf(v0, w.w, a0.w);
        a1.x = fmaf(v1, w.x, a1.x); a1.y = fmaf(v1, w.y, a1.y);
        a1.z = fmaf(v1, w.z, a1.z); a1.w = fmaf(v1, w.w, a1.w);
    }
    const int gr0 = row0 + r0, gr1 = row0 + r1;
    if (gr0 < N) *reinterpret_cast<float4*>(&C[(size_t)gr0 * COUT + cg * 4]) = a0;
    if (gr1 < N) *reinterpret_cast<float4*>(&C[(size_t)gr1 * COUT + cg * 4]) = a1;
}

// ---------------- edge aggregation: sum[dst] += T[src], wave per edge ----------------
template <int C>
__global__ __launch_bounds__(256) void agg_kernel(
    const float* __restrict__ T, const int* __restrict__ edges, // [0..E)=src, [E..2E)=dst
    float* __restrict__ sum, int E)
{
    int t = blockIdx.x * 256 + threadIdx.x;
    int e = t >> 6;
    int lane = t & 63;
    if (e >= E) return;
    int s = edges[e];
    int d = edges[E + e];
    if (C == 128) {
        float2 v = *reinterpret_cast<const float2*>(&T[(size_t)s * 128 + lane * 2]);
        atomicAdd(&sum[(size_t)d * 128 + lane * 2], v.x);
        atomicAdd(&sum[(size_t)d * 128 + lane * 2 + 1], v.y);
    } else {
        float v = T[(size_t)s * 64 + lane];
        atomicAdd(&sum[(size_t)d * 64 + lane], v);
    }
}

// ---------------- combine: out = [relu](sum/deg + bias + r) ----------------
template <int C, bool RELU>
__global__ __launch_bounds__(256) void combine_kernel(
    const float* __restrict__ sum, const float* __restrict__ r,
    const float* __restrict__ deg, const float* __restrict__ bias,
    float* __restrict__ out, int N)
{
    constexpr int CG = C / 4;
    int idx = blockIdx.x * blockDim.x + threadIdx.x;
    int total = N * CG;
    if (idx >= total) return;
    int n = idx / CG;
    int cg = idx % CG;
    float inv = 1.0f / fmaxf(deg[n], 1.0f);
    float4 s = *reinterpret_cast<const float4*>(&sum[(size_t)idx * 4]);
    float4 rr = *reinterpret_cast<const float4*>(&r[(size_t)idx * 4]);
    float4 b = *reinterpret_cast<const float4*>(&bias[cg * 4]);
    float4 o;
    o.x = fmaf(s.x, inv, b.x) + rr.x;
    o.y = fmaf(s.y, inv, b.y) + rr.y;
    o.z = fmaf(s.z, inv, b.z) + rr.z;
    o.w = fmaf(s.w, inv, b.w) + rr.w;
    if (RELU) {
        o.x = fmaxf(o.x, 0.f); o.y = fmaxf(o.y, 0.f);
        o.z = fmaxf(o.z, 0.f); o.w = fmaxf(o.w, 0.f);
    }
    *reinterpret_cast<float4*>(&out[(size_t)idx * 4]) = o;
}

// ---------------- decode: wave per pair, shuffle reduce ----------------
__global__ __launch_bounds__(256) void decode_kernel(
    const float* __restrict__ z, const int* __restrict__ eli,
    const float* __restrict__ Wdec, const float* __restrict__ bdec,
    float* __restrict__ out, int P)
{
    int t = blockIdx.x * 256 + threadIdx.x;
    int p = t >> 6;
    int lane = t & 63;
    if (p >= P) return;
    int a = eli[p];
    int b = eli[P + p];
    float acc = z[(size_t)a * 64 + lane] * Wdec[lane]
              + z[(size_t)b * 64 + lane] * Wdec[64 + lane];
    for (int off = 32; off; off >>= 1) acc += __shfl_down(acc, off);
    if (lane == 0) out[p] = acc + bdec[0];
}

extern "C" void kernel_launch(void* const* d_in, const int* in_sizes, int n_in,
                              void* d_out, int out_size, void* d_ws, size_t ws_size,
                              hipStream_t stream) {
    const float* x    = (const float*)d_in[0];
    const int*   ei   = (const int*)d_in[1];
    const int*   eli  = (const int*)d_in[2];
    const float* Wl1  = (const float*)d_in[3];
    const float* bl1  = (const float*)d_in[4];
    const float* Wr1  = (const float*)d_in[5];
    const float* Wl2  = (const float*)d_in[6];
    const float* bl2  = (const float*)d_in[7];
    const float* Wr2  = (const float*)d_in[8];
    const float* Wdec = (const float*)d_in[9];
    const float* bdec = (const float*)d_in[10];
    float* out = (float*)d_out;

    const int N = NN;
    const int E = in_sizes[1] / 2;
    const int P = in_sizes[2] / 2;

    float* ws   = (float*)d_ws;
    float* deg  = ws;                         // [N]
    float* bufA = ws + N;                     // [N*128] t1 -> h
    float* bufB = bufA + (size_t)N * 128;     // [N*128] r1 -> t2(lower) + r2(upper)
    float* bufC = bufB + (size_t)N * 128;     // [N*128] sum1 -> sum2(lower) + z(upper)

    // zero deg + sum1
    zero_kernel<<<2048, 256, 0, stream>>>(deg, N / 4);
    zero_kernel<<<2048, 256, 0, stream>>>(bufC, (long)N * 128 / 4);

    deg_kernel<<<(E + 255) / 256, 256, 0, stream>>>(ei + E, deg, E);

    // layer 1: t1 = x@Wl1^T, r1 = x@Wr1^T
    gemm_kernel<128, 128><<<(N + 63) / 64, 1024, 0, stream>>>(x, Wl1, bufA, N);
    gemm_kernel<128, 128><<<(N + 63) / 64, 1024, 0, stream>>>(x, Wr1, bufB, N);
    // sum1[dst] += t1[src]
    agg_kernel<128><<<(E + 3) / 4, 256, 0, stream>>>(bufA, ei, bufC, E);
    // h = relu(sum1/deg + bl1 + r1) -> bufA
    combine_kernel<128, true><<<(N * 32 + 255) / 256, 256, 0, stream>>>(
        bufC, bufB, deg, bl1, bufA, N);

    // layer 2: t2 = h@Wl2^T -> bufB[0:N*64], r2 = h@Wr2^T -> bufB[N*64:]
    gemm_kernel<128, 64><<<(N + 127) / 128, 1024, 0, stream>>>(bufA, Wl2, bufB, N);
    gemm_kernel<128, 64><<<(N + 127) / 128, 1024, 0, stream>>>(bufA, Wr2, bufB + (size_t)N * 64, N);
    // zero sum2, aggregate
    zero_kernel<<<2048, 256, 0, stream>>>(bufC, (long)N * 64 / 4);
    agg_kernel<64><<<(E + 3) / 4, 256, 0, stream>>>(bufB, ei, bufC, E);
    // z = sum2/deg + bl2 + r2 -> bufC[N*64:]
    combine_kernel<64, false><<<(N * 16 + 255) / 256, 256, 0, stream>>>(
        bufC, bufB + (size_t)N * 64, deg, bl2, bufC + (size_t)N * 64, N);

    // decode
    decode_kernel<<<(P + 3) / 4, 256, 0, stream>>>(
        bufC + (size_t)N * 64, eli, Wdec, bdec, out, P);
}

// Round 2
// 789.837 us; speedup vs baseline: 2.6997x; 2.6997x over previous
//
#include <hip/hip_runtime.h>

#define NN 100000

// ---------------- zero fill (float4 grid-stride; also used for int buffers) ----
__global__ void zero_kernel(float* __restrict__ p, long n4) {
    long i = (long)blockIdx.x * blockDim.x + threadIdx.x;
    long stride = (long)gridDim.x * blockDim.x;
    for (long j = i; j < n4; j += stride) {
        reinterpret_cast<float4*>(p)[j] = make_float4(0.f, 0.f, 0.f, 0.f);
    }
}

// ---------------- degree histogram (int atomics) ----------------
__global__ void count_kernel(const int* __restrict__ dst, int* __restrict__ cnt, int E) {
    int e = blockIdx.x * blockDim.x + threadIdx.x;
    if (e < E) atomicAdd(&cnt[dst[e]], 1);
}

// ---------------- scan step 1: per-block exclusive scan + block sums ----------
__global__ void scan1_kernel(const int* __restrict__ cnt, int* __restrict__ excl,
                             int* __restrict__ blockSums, int n) {
    __shared__ int s[256];
    int tid = threadIdx.x;
    int i = blockIdx.x * 256 + tid;
    int v = (i < n) ? cnt[i] : 0;
    s[tid] = v;
    __syncthreads();
    for (int off = 1; off < 256; off <<= 1) {
        int t = (tid >= off) ? s[tid - off] : 0;
        __syncthreads();
        s[tid] += t;
        __syncthreads();
    }
    if (i < n) excl[i] = s[tid] - v;
    if (tid == 255) blockSums[blockIdx.x] = s[255];
}

// ---------------- scan step 2: single-block exclusive scan of block sums ------
__global__ void scan2_kernel(int* __restrict__ blockSums, int nb) {
    __shared__ int s[512];
    int tid = threadIdx.x;
    int v = (tid < nb) ? blockSums[tid] : 0;
    s[tid] = v;
    __syncthreads();
    for (int off = 1; off < 512; off <<= 1) {
        int t = (tid >= off) ? s[tid - off] : 0;
        __syncthreads();
        s[tid] += t;
        __syncthreads();
    }
    if (tid < nb) blockSums[tid] = s[tid] - v;
}

// ---------------- scan step 3: finalize rowStart, init cursors ----------------
__global__ void scan3_kernel(int* __restrict__ rowStart, int* __restrict__ cursors,
                             const int* __restrict__ blockSums, int n) {
    int i = blockIdx.x * blockDim.x + threadIdx.x;
    if (i < n) {
        int v = rowStart[i] + blockSums[i >> 8];
        rowStart[i] = v;
        cursors[i] = v;
    }
}

// ---------------- scatter src ids into dst-sorted order -----------------------
__global__ void scatter_kernel(const int* __restrict__ edges, int* __restrict__ cursors,
                               int* __restrict__ sortedSrc, int E) {
    int e = blockIdx.x * blockDim.x + threadIdx.x;
    if (e < E) {
        int d = edges[E + e];
        int pos = atomicAdd(&cursors[d], 1);
        sortedSrc[pos] = edges[e];
    }
}

// ---------------- GEMM: C[N,COUT] = X[N,CIN] @ W[COUT,CIN]^T ----------------
template <int CIN, int COUT>
__global__ __launch_bounds__(1024) void gemm_kernel(
    const float* __restrict__ X, const float* __restrict__ W,
    float* __restrict__ C, int N)
{
    constexpr int COLG = COUT / 4;          // float4 column groups
    constexpr int ROWS = (1024 / COLG) * 2; // rows per block (2 per thread)
    __shared__ float wt[CIN * COUT];        // wt[k*COUT + c] = W[c*CIN + k]
    __shared__ float xs[ROWS * CIN];

    const int tid = threadIdx.x;
    for (int i = tid; i < CIN * COUT; i += 1024) {
        int c = i % COUT, k = i / COUT;
        wt[k * COUT + c] = W[c * CIN + k];
    }
    const int row0 = blockIdx.x * ROWS;
    for (int i = tid * 4; i < ROWS * CIN; i += 1024 * 4) {
        int r = i / CIN;
        int gr = row0 + r;
        float4 v = make_float4(0.f, 0.f, 0.f, 0.f);
        if (gr < N) v = *reinterpret_cast<const float4*>(&X[(size_t)gr * CIN + (i % CIN)]);
        *reinterpret_cast<float4*>(&xs[i]) = v;
    }
    __syncthreads();

    const int cg = tid % COLG;
    const int rs = tid / COLG;
    const int r0 = rs * 2, r1 = r0 + 1;
    const float* __restrict__ xp0 = &xs[r0 * CIN];
    const float* __restrict__ xp1 = &xs[r1 * CIN];

    float4 a0 = make_float4(0.f, 0.f, 0.f, 0.f);
    float4 a1 = make_float4(0.f, 0.f, 0.f, 0.f);
#pragma unroll 4
    for (int k = 0; k < CIN; ++k) {
        float4 w = *reinterpret_cast<const float4*>(&wt[k * COUT + cg * 4]);
        float v0 = xp0[k], v1 = xp1[k];
        a0.x = fmaf(v0, w.x, a0.x); a0.y = fmaf(v0, w.y, a0.y);
        a0.z = fmaf(v0, w.z, a0.z); a0.w = fmaf(v0, w.w, a0.w);
        a1.x = fmaf(v1, w.x, a1.x); a1.y = fmaf(v1, w.y, a1.y);
        a1.z = fmaf(v1, w.z, a1.z); a1.w = fmaf(v1, w.w, a1.w);
    }
    const int gr0 = row0 + r0, gr1 = row0 + r1;
    if (gr0 < N) *reinterpret_cast<float4*>(&C[(size_t)gr0 * COUT + cg * 4]) = a0;
    if (gr1 < N) *reinterpret_cast<float4*>(&C[(size_t)gr1 * COUT + cg * 4]) = a1;
}

// ---------------- gather aggregation: sum[n] = sum_{e in CSR[n]} T[src[e]] ----
// One node per (C/2) threads, float2 per thread, 4-deep unrolled gathers.
template <int C>
__global__ __launch_bounds__(256) void agg_gather_kernel(
    const float* __restrict__ T, const int* __restrict__ sortedSrc,
    const int* __restrict__ rowStart, const int* __restrict__ cnt,
    float* __restrict__ sum, int N)
{
    constexpr int TPN = C / 2;          // threads per node (float2 each)
    constexpr int NPB = 256 / TPN;      // nodes per block
    int n = blockIdx.x * NPB + threadIdx.x / TPN;
    int c = threadIdx.x % TPN;          // float2 index
    if (n >= N) return;
    int start = rowStart[n];
    int m = cnt[n];
    const int* __restrict__ ep = sortedSrc + start;

    float ax = 0.f, ay = 0.f;
    int k = 0;
    for (; k + 4 <= m; k += 4) {
        int s0 = ep[k], s1 = ep[k + 1], s2 = ep[k + 2], s3 = ep[k + 3];
        float2 v0 = *reinterpret_cast<const float2*>(&T[(size_t)s0 * C + c * 2]);
        float2 v1 = *reinterpret_cast<const float2*>(&T[(size_t)s1 * C + c * 2]);
        float2 v2 = *reinterpret_cast<const float2*>(&T[(size_t)s2 * C + c * 2]);
        float2 v3 = *reinterpret_cast<const float2*>(&T[(size_t)s3 * C + c * 2]);
        ax += (v0.x + v1.x) + (v2.x + v3.x);
        ay += (v0.y + v1.y) + (v2.y + v3.y);
    }
    for (; k < m; ++k) {
        int s = ep[k];
        float2 v = *reinterpret_cast<const float2*>(&T[(size_t)s * C + c * 2]);
        ax += v.x; ay += v.y;
    }
    float2 o; o.x = ax; o.y = ay;
    *reinterpret_cast<float2*>(&sum[(size_t)n * C + c * 2]) = o;
}

// ---------------- combine: out = [relu](sum/deg + bias + r) ----------------
template <int C, bool RELU>
__global__ __launch_bounds__(256) void combine_kernel(
    const float* __restrict__ sum, const float* __restrict__ r,
    const int* __restrict__ cnt, const float* __restrict__ bias,
    float* __restrict__ out, int N)
{
    constexpr int CG = C / 4;
    int idx = blockIdx.x * blockDim.x + threadIdx.x;
    int total = N * CG;
    if (idx >= total) return;
    int n = idx / CG;
    int cg = idx % CG;
    float inv = 1.0f / fmaxf((float)cnt[n], 1.0f);
    float4 s = *reinterpret_cast<const float4*>(&sum[(size_t)idx * 4]);
    float4 rr = *reinterpret_cast<const float4*>(&r[(size_t)idx * 4]);
    float4 b = *reinterpret_cast<const float4*>(&bias[cg * 4]);
    float4 o;
    o.x = fmaf(s.x, inv, b.x) + rr.x;
    o.y = fmaf(s.y, inv, b.y) + rr.y;
    o.z = fmaf(s.z, inv, b.z) + rr.z;
    o.w = fmaf(s.w, inv, b.w) + rr.w;
    if (RELU) {
        o.x = fmaxf(o.x, 0.f); o.y = fmaxf(o.y, 0.f);
        o.z = fmaxf(o.z, 0.f); o.w = fmaxf(o.w, 0.f);
    }
    *reinterpret_cast<float4*>(&out[(size_t)idx * 4]) = o;
}

// ---------------- decode: wave per pair, shuffle reduce ----------------
__global__ __launch_bounds__(256) void decode_kernel(
    const float* __restrict__ z, const int* __restrict__ eli,
    const float* __restrict__ Wdec, const float* __restrict__ bdec,
    float* __restrict__ out, int P)
{
    int t = blockIdx.x * 256 + threadIdx.x;
    int p = t >> 6;
    int lane = t & 63;
    if (p >= P) return;
    int a = eli[p];
    int b = eli[P + p];
    float acc = z[(size_t)a * 64 + lane] * Wdec[lane]
              + z[(size_t)b * 64 + lane] * Wdec[64 + lane];
    for (int off = 32; off; off >>= 1) acc += __shfl_down(acc, off);
    if (lane == 0) out[p] = acc + bdec[0];
}

extern "C" void kernel_launch(void* const* d_in, const int* in_sizes, int n_in,
                              void* d_out, int out_size, void* d_ws, size_t ws_size,
                              hipStream_t stream) {
    const float* x    = (const float*)d_in[0];
    const int*   ei   = (const int*)d_in[1];
    const int*   eli  = (const int*)d_in[2];
    const float* Wl1  = (const float*)d_in[3];
    const float* bl1  = (const float*)d_in[4];
    const float* Wr1  = (const float*)d_in[5];
    const float* Wl2  = (const float*)d_in[6];
    const float* bl2  = (const float*)d_in[7];
    const float* Wr2  = (const float*)d_in[8];
    const float* Wdec = (const float*)d_in[9];
    const float* bdec = (const float*)d_in[10];
    float* out = (float*)d_out;

    const int N = NN;
    const int E = in_sizes[1] / 2;
    const int P = in_sizes[2] / 2;
    const int NB = (N + 255) / 256;   // scan blocks (391)

    float* ws   = (float*)d_ws;
    float* bufA = ws;                         // [N*128] t1 -> h
    float* bufB = bufA + (size_t)N * 128;     // [N*128] r1 -> t2(lower) + r2(upper)
    float* bufC = bufB + (size_t)N * 128;     // [N*128] sum1 -> sum2(lower) + z(upper)
    int* cnt       = (int*)(bufC + (size_t)N * 128); // [N]
    int* rowStart  = cnt + N;                        // [N]
    int* cursors   = rowStart + N;                   // [N]
    int* blockSums = cursors + N;                    // [512]
    int* sortedSrc = blockSums + 512;                // [E]

    // ---- build CSR by dst ----
    zero_kernel<<<128, 256, 0, stream>>>((float*)cnt, N / 4);
    count_kernel<<<(E + 255) / 256, 256, 0, stream>>>(ei + E, cnt, E);
    scan1_kernel<<<NB, 256, 0, stream>>>(cnt, rowStart, blockSums, N);
    scan2_kernel<<<1, 512, 0, stream>>>(blockSums, NB);
    scan3_kernel<<<NB, 256, 0, stream>>>(rowStart, cursors, blockSums, N);
    scatter_kernel<<<(E + 255) / 256, 256, 0, stream>>>(ei, cursors, sortedSrc, E);

    // ---- layer 1: t1 = x@Wl1^T, r1 = x@Wr1^T ----
    gemm_kernel<128, 128><<<(N + 63) / 64, 1024, 0, stream>>>(x, Wl1, bufA, N);
    gemm_kernel<128, 128><<<(N + 63) / 64, 1024, 0, stream>>>(x, Wr1, bufB, N);
    agg_gather_kernel<128><<<(N + 3) / 4, 256, 0, stream>>>(bufA, sortedSrc, rowStart, cnt, bufC, N);
    combine_kernel<128, true><<<(N * 32 + 255) / 256, 256, 0, stream>>>(
        bufC, bufB, cnt, bl1, bufA, N);

    // ---- layer 2: t2 = h@Wl2^T, r2 = h@Wr2^T ----
    gemm_kernel<128, 64><<<(N + 127) / 128, 1024, 0, stream>>>(bufA, Wl2, bufB, N);
    gemm_kernel<128, 64><<<(N + 127) / 128, 1024, 0, stream>>>(bufA, Wr2, bufB + (size_t)N * 64, N);
    agg_gather_kernel<64><<<(N + 7) / 8, 256, 0, stream>>>(bufB, sortedSrc, rowStart, cnt, bufC, N);
    combine_kernel<64, false><<<(N * 16 + 255) / 256, 256, 0, stream>>>(
        bufC, bufB + (size_t)N * 64, cnt, bl2, bufC + (size_t)N * 64, N);

    // ---- decode ----
    decode_kernel<<<(P + 3) / 4, 256, 0, stream>>>(
        bufC + (size_t)N * 64, eli, Wdec, bdec, out, P);
}

// Round 3
// 644.257 us; speedup vs baseline: 3.3097x; 1.2260x over previous
//
#include <hip/hip_runtime.h>

#define NN 100000
#define NBUK ((NN + 255) / 256)   // 391 dst buckets of 256 nodes

// ---------------- tiny zero for bucket counters ----------------
__global__ void zero_buckets_kernel(int* __restrict__ p) {
    int i = threadIdx.x;
    if (i < NBUK) p[i] = 0;
}

// ---------------- bucket histogram (LDS pre-aggregated) ----------------
__global__ __launch_bounds__(256) void hist_kernel(const int* __restrict__ dst,
                                                   int* __restrict__ bucketCnt, int E) {
    __shared__ int h[NBUK];
    for (int i = threadIdx.x; i < NBUK; i += 256) h[i] = 0;
    __syncthreads();
    int base = blockIdx.x * 4096;
    for (int k = threadIdx.x; k < 4096; k += 256) {
        int e = base + k;
        if (e < E) atomicAdd(&h[dst[e] >> 8], 1);
    }
    __syncthreads();
    for (int i = threadIdx.x; i < NBUK; i += 256)
        if (h[i]) atomicAdd(&bucketCnt[i], h[i]);
}

// ---------------- scan bucket counts -> bucketStart[NBUK+1], init cursors ----
__global__ void bucket_scan_kernel(const int* __restrict__ bucketCnt,
                                   int* __restrict__ bucketStart,
                                   int* __restrict__ bucketCursor) {
    __shared__ int s[512];
    int tid = threadIdx.x;
    int v = (tid < NBUK) ? bucketCnt[tid] : 0;
    s[tid] = v;
    __syncthreads();
    for (int off = 1; off < 512; off <<= 1) {
        int t = (tid >= off) ? s[tid - off] : 0;
        __syncthreads();
        s[tid] += t;
        __syncthreads();
    }
    if (tid < NBUK) {
        int st = s[tid] - v;
        bucketStart[tid] = st;
        bucketCursor[tid] = st;
    }
    if (tid == NBUK - 1) bucketStart[NBUK] = s[tid];
}

// ---------------- partition edges into dst buckets (packed src|dstlow) -------
__global__ __launch_bounds__(256) void partition_kernel(const int* __restrict__ edges,
                                                        int* __restrict__ bucketCursor,
                                                        int* __restrict__ bucketed, int E) {
    __shared__ int h[NBUK];
    __shared__ int base[NBUK];
    for (int i = threadIdx.x; i < NBUK; i += 256) h[i] = 0;
    __syncthreads();
    int b0 = blockIdx.x * 4096;
    for (int k = threadIdx.x; k < 4096; k += 256) {
        int e = b0 + k;
        if (e < E) atomicAdd(&h[edges[E + e] >> 8], 1);
    }
    __syncthreads();
    for (int i = threadIdx.x; i < NBUK; i += 256) {
        int c = h[i];
        base[i] = c ? atomicAdd(&bucketCursor[i], c) : 0;
        h[i] = 0;  // reuse as intra-block offset
    }
    __syncthreads();
    for (int k = threadIdx.x; k < 4096; k += 256) {
        int e = b0 + k;
        if (e < E) {
            int d = edges[E + e];
            int b = d >> 8;
            int off = atomicAdd(&h[b], 1);
            bucketed[base[b] + off] = edges[e] | ((d & 255) << 20);
        }
    }
}

// ---------------- per-bucket counting sort -> rowStart, cnt, sortedSrc -------
__global__ __launch_bounds__(256) void bucket_sort_kernel(const int* __restrict__ bucketed,
                                                          const int* __restrict__ bucketStart,
                                                          int* __restrict__ rowStart,
                                                          int* __restrict__ cnt,
                                                          int* __restrict__ sortedSrc, int N) {
    __shared__ int h[256];
    __shared__ int pos[256];
    int b = blockIdx.x;
    int tid = threadIdx.x;
    int start = bucketStart[b], end = bucketStart[b + 1];
    h[tid] = 0;
    __syncthreads();
    for (int k = start + tid; k < end; k += 256) atomicAdd(&h[bucketed[k] >> 20], 1);
    __syncthreads();
    int v = h[tid];
    pos[tid] = v;
    __syncthreads();
    for (int off = 1; off < 256; off <<= 1) {
        int t = (tid >= off) ? pos[tid - off] : 0;
        __syncthreads();
        pos[tid] += t;
        __syncthreads();
    }
    int excl = start + pos[tid] - v;
    int node = (b << 8) + tid;
    if (node < N) {
        rowStart[node] = excl;
        cnt[node] = v;
    }
    h[tid] = excl;  // reuse as per-node cursor
    __syncthreads();
    for (int k = start + tid; k < end; k += 256) {
        int entry = bucketed[k];
        int p = atomicAdd(&h[entry >> 20], 1);
        sortedSrc[p] = entry & 0xFFFFF;
    }
}

// ---------------- GEMM: C[N,COUT] = X[N,CIN] @ W[COUT,CIN]^T ----------------
template <int CIN, int COUT>
__global__ __launch_bounds__(1024) void gemm_kernel(
    const float* __restrict__ X, const float* __restrict__ W,
    float* __restrict__ C, int N)
{
    constexpr int COLG = COUT / 4;          // float4 column groups
    constexpr int ROWS = (1024 / COLG) * 2; // rows per block (2 per thread)
    __shared__ float wt[CIN * COUT];        // wt[k*COUT + c] = W[c*CIN + k]
    __shared__ float xs[ROWS * CIN];

    const int tid = threadIdx.x;
    for (int i = tid; i < CIN * COUT; i += 1024) {
        int c = i % COUT, k = i / COUT;
        wt[k * COUT + c] = W[c * CIN + k];
    }
    const int row0 = blockIdx.x * ROWS;
    for (int i = tid * 4; i < ROWS * CIN; i += 1024 * 4) {
        int r = i / CIN;
        int gr = row0 + r;
        float4 v = make_float4(0.f, 0.f, 0.f, 0.f);
        if (gr < N) v = *reinterpret_cast<const float4*>(&X[(size_t)gr * CIN + (i % CIN)]);
        *reinterpret_cast<float4*>(&xs[i]) = v;
    }
    __syncthreads();

    const int cg = tid % COLG;
    const int rs = tid / COLG;
    const int r0 = rs * 2, r1 = r0 + 1;
    const float* __restrict__ xp0 = &xs[r0 * CIN];
    const float* __restrict__ xp1 = &xs[r1 * CIN];

    float4 a0 = make_float4(0.f, 0.f, 0.f, 0.f);
    float4 a1 = make_float4(0.f, 0.f, 0.f, 0.f);
#pragma unroll 4
    for (int k = 0; k < CIN; ++k) {
        float4 w = *reinterpret_cast<const float4*>(&wt[k * COUT + cg * 4]);
        float v0 = xp0[k], v1 = xp1[k];
        a0.x = fmaf(v0, w.x, a0.x); a0.y = fmaf(v0, w.y, a0.y);
        a0.z = fmaf(v0, w.z, a0.z); a0.w = fmaf(v0, w.w, a0.w);
        a1.x = fmaf(v1, w.x, a1.x); a1.y = fmaf(v1, w.y, a1.y);
        a1.z = fmaf(v1, w.z, a1.z); a1.w = fmaf(v1, w.w, a1.w);
    }
    const int gr0 = row0 + r0, gr1 = row0 + r1;
    if (gr0 < N) *reinterpret_cast<float4*>(&C[(size_t)gr0 * COUT + cg * 4]) = a0;
    if (gr1 < N) *reinterpret_cast<float4*>(&C[(size_t)gr1 * COUT + cg * 4]) = a1;
}

// ---------------- gather aggregation: sum[n] = sum_{e in CSR[n]} T[src[e]] ----
template <int C>
__global__ __launch_bounds__(256) void agg_gather_kernel(
    const float* __restrict__ T, const int* __restrict__ sortedSrc,
    const int* __restrict__ rowStart, const int* __restrict__ cnt,
    float* __restrict__ sum, int N)
{
    constexpr int TPN = C / 2;          // threads per node (float2 each)
    constexpr int NPB = 256 / TPN;      // nodes per block
    int n = blockIdx.x * NPB + threadIdx.x / TPN;
    int c = threadIdx.x % TPN;          // float2 index
    if (n >= N) return;
    int start = rowStart[n];
    int m = cnt[n];
    const int* __restrict__ ep = sortedSrc + start;

    float ax = 0.f, ay = 0.f;
    int k = 0;
    for (; k + 4 <= m; k += 4) {
        int s0 = ep[k], s1 = ep[k + 1], s2 = ep[k + 2], s3 = ep[k + 3];
        float2 v0 = *reinterpret_cast<const float2*>(&T[(size_t)s0 * C + c * 2]);
        float2 v1 = *reinterpret_cast<const float2*>(&T[(size_t)s1 * C + c * 2]);
        float2 v2 = *reinterpret_cast<const float2*>(&T[(size_t)s2 * C + c * 2]);
        float2 v3 = *reinterpret_cast<const float2*>(&T[(size_t)s3 * C + c * 2]);
        ax += (v0.x + v1.x) + (v2.x + v3.x);
        ay += (v0.y + v1.y) + (v2.y + v3.y);
    }
    for (; k < m; ++k) {
        int s = ep[k];
        float2 v = *reinterpret_cast<const float2*>(&T[(size_t)s * C + c * 2]);
        ax += v.x; ay += v.y;
    }
    float2 o; o.x = ax; o.y = ay;
    *reinterpret_cast<float2*>(&sum[(size_t)n * C + c * 2]) = o;
}

// ---------------- combine: out = [relu](sum/deg + bias + r) ----------------
template <int C, bool RELU>
__global__ __launch_bounds__(256) void combine_kernel(
    const float* __restrict__ sum, const float* __restrict__ r,
    const int* __restrict__ cnt, const float* __restrict__ bias,
    float* __restrict__ out, int N)
{
    constexpr int CG = C / 4;
    int idx = blockIdx.x * blockDim.x + threadIdx.x;
    int total = N * CG;
    if (idx >= total) return;
    int n = idx / CG;
    int cg = idx % CG;
    float inv = 1.0f / fmaxf((float)cnt[n], 1.0f);
    float4 s = *reinterpret_cast<const float4*>(&sum[(size_t)idx * 4]);
    float4 rr = *reinterpret_cast<const float4*>(&r[(size_t)idx * 4]);
    float4 b = *reinterpret_cast<const float4*>(&bias[cg * 4]);
    float4 o;
    o.x = fmaf(s.x, inv, b.x) + rr.x;
    o.y = fmaf(s.y, inv, b.y) + rr.y;
    o.z = fmaf(s.z, inv, b.z) + rr.z;
    o.w = fmaf(s.w, inv, b.w) + rr.w;
    if (RELU) {
        o.x = fmaxf(o.x, 0.f); o.y = fmaxf(o.y, 0.f);
        o.z = fmaxf(o.z, 0.f); o.w = fmaxf(o.w, 0.f);
    }
    *reinterpret_cast<float4*>(&out[(size_t)idx * 4]) = o;
}

// ---------------- decode: wave per pair, shuffle reduce ----------------
__global__ __launch_bounds__(256) void decode_kernel(
    const float* __restrict__ z, const int* __restrict__ eli,
    const float* __restrict__ Wdec, const float* __restrict__ bdec,
    float* __restrict__ out, int P)
{
    int t = blockIdx.x * 256 + threadIdx.x;
    int p = t >> 6;
    int lane = t & 63;
    if (p >= P) return;
    int a = eli[p];
    int b = eli[P + p];
    float acc = z[(size_t)a * 64 + lane] * Wdec[lane]
              + z[(size_t)b * 64 + lane] * Wdec[64 + lane];
    for (int off = 32; off; off >>= 1) acc += __shfl_down(acc, off);
    if (lane == 0) out[p] = acc + bdec[0];
}

extern "C" void kernel_launch(void* const* d_in, const int* in_sizes, int n_in,
                              void* d_out, int out_size, void* d_ws, size_t ws_size,
                              hipStream_t stream) {
    const float* x    = (const float*)d_in[0];
    const int*   ei   = (const int*)d_in[1];
    const int*   eli  = (const int*)d_in[2];
    const float* Wl1  = (const float*)d_in[3];
    const float* bl1  = (const float*)d_in[4];
    const float* Wr1  = (const float*)d_in[5];
    const float* Wl2  = (const float*)d_in[6];
    const float* bl2  = (const float*)d_in[7];
    const float* Wr2  = (const float*)d_in[8];
    const float* Wdec = (const float*)d_in[9];
    const float* bdec = (const float*)d_in[10];
    float* out = (float*)d_out;

    const int N = NN;
    const int E = in_sizes[1] / 2;
    const int P = in_sizes[2] / 2;
    const int EB = (E + 4095) / 4096;  // edge-chunk blocks (391 for E=1.6M)

    float* ws   = (float*)d_ws;
    float* bufA = ws;                         // [N*128] t1 -> h
    float* bufB = bufA + (size_t)N * 128;     // [N*128] r1 -> t2(lower) + r2(upper)
    float* bufC = bufB + (size_t)N * 128;     // [N*128] sum1 -> sum2(lower) + z(upper)
    int* bucketCnt    = (int*)(bufC + (size_t)N * 128); // [NBUK]
    int* bucketStart  = bucketCnt + NBUK;               // [NBUK+1]
    int* bucketCursor = bucketStart + NBUK + 1;         // [NBUK]
    int* rowStart     = bucketCursor + NBUK;            // [N]
    int* cnt          = rowStart + N;                   // [N]
    int* bucketed     = cnt + N;                        // [E]
    int* sortedSrc    = bucketed + E;                   // [E]

    // ---- build CSR by dst (radix partition + per-bucket counting sort) ----
    zero_buckets_kernel<<<1, 512, 0, stream>>>(bucketCnt);
    hist_kernel<<<EB, 256, 0, stream>>>(ei + E, bucketCnt, E);
    bucket_scan_kernel<<<1, 512, 0, stream>>>(bucketCnt, bucketStart, bucketCursor);
    partition_kernel<<<EB, 256, 0, stream>>>(ei, bucketCursor, bucketed, E);
    bucket_sort_kernel<<<NBUK, 256, 0, stream>>>(bucketed, bucketStart, rowStart, cnt, sortedSrc, N);

    // ---- layer 1: t1 = x@Wl1^T, r1 = x@Wr1^T ----
    gemm_kernel<128, 128><<<(N + 63) / 64, 1024, 0, stream>>>(x, Wl1, bufA, N);
    gemm_kernel<128, 128><<<(N + 63) / 64, 1024, 0, stream>>>(x, Wr1, bufB, N);
    agg_gather_kernel<128><<<(N + 3) / 4, 256, 0, stream>>>(bufA, sortedSrc, rowStart, cnt, bufC, N);
    combine_kernel<128, true><<<(N * 32 + 255) / 256, 256, 0, stream>>>(
        bufC, bufB, cnt, bl1, bufA, N);

    // ---- layer 2: t2 = h@Wl2^T, r2 = h@Wr2^T ----
    gemm_kernel<128, 64><<<(N + 127) / 128, 1024, 0, stream>>>(bufA, Wl2, bufB, N);
    gemm_kernel<128, 64><<<(N + 127) / 128, 1024, 0, stream>>>(bufA, Wr2, bufB + (size_t)N * 64, N);
    agg_gather_kernel<64><<<(N + 7) / 8, 256, 0, stream>>>(bufB, sortedSrc, rowStart, cnt, bufC, N);
    combine_kernel<64, false><<<(N * 16 + 255) / 256, 256, 0, stream>>>(
        bufC, bufB + (size_t)N * 64, cnt, bl2, bufC + (size_t)N * 64, N);

    // ---- decode ----
    decode_kernel<<<(P + 3) / 4, 256, 0, stream>>>(
        bufC + (size_t)N * 64, eli, Wdec, bdec, out, P);
}

// Round 4
// 462.607 us; speedup vs baseline: 4.6093x; 1.3927x over previous
//
#include <hip/hip_runtime.h>

#define NN 100000
#define NBUK ((NN + 255) / 256)   // 391 dst buckets of 256 nodes

// ---------------- tiny zero for bucket counters ----------------
__global__ void zero_buckets_kernel(int* __restrict__ p) {
    int i = threadIdx.x;
    if (i < NBUK) p[i] = 0;
}

// ---------------- bucket histogram (LDS pre-aggregated) ----------------
__global__ __launch_bounds__(256) void hist_kernel(const int* __restrict__ dst,
                                                   int* __restrict__ bucketCnt, int E) {
    __shared__ int h[NBUK];
    for (int i = threadIdx.x; i < NBUK; i += 256) h[i] = 0;
    __syncthreads();
    int base = blockIdx.x * 4096;
    for (int k = threadIdx.x; k < 4096; k += 256) {
        int e = base + k;
        if (e < E) atomicAdd(&h[dst[e] >> 8], 1);
    }
    __syncthreads();
    for (int i = threadIdx.x; i < NBUK; i += 256)
        if (h[i]) atomicAdd(&bucketCnt[i], h[i]);
}

// ---------------- scan bucket counts -> bucketStart[NBUK+1], init cursors ----
__global__ void bucket_scan_kernel(const int* __restrict__ bucketCnt,
                                   int* __restrict__ bucketStart,
                                   int* __restrict__ bucketCursor) {
    __shared__ int s[512];
    int tid = threadIdx.x;
    int v = (tid < NBUK) ? bucketCnt[tid] : 0;
    s[tid] = v;
    __syncthreads();
    for (int off = 1; off < 512; off <<= 1) {
        int t = (tid >= off) ? s[tid - off] : 0;
        __syncthreads();
        s[tid] += t;
        __syncthreads();
    }
    if (tid < NBUK) {
        int st = s[tid] - v;
        bucketStart[tid] = st;
        bucketCursor[tid] = st;
    }
    if (tid == NBUK - 1) bucketStart[NBUK] = s[tid];
}

// ---------------- partition edges into dst buckets (packed src|dstlow) -------
__global__ __launch_bounds__(256) void partition_kernel(const int* __restrict__ edges,
                                                        int* __restrict__ bucketCursor,
                                                        int* __restrict__ bucketed, int E) {
    __shared__ int h[NBUK];
    __shared__ int base[NBUK];
    for (int i = threadIdx.x; i < NBUK; i += 256) h[i] = 0;
    __syncthreads();
    int b0 = blockIdx.x * 4096;
    for (int k = threadIdx.x; k < 4096; k += 256) {
        int e = b0 + k;
        if (e < E) atomicAdd(&h[edges[E + e] >> 8], 1);
    }
    __syncthreads();
    for (int i = threadIdx.x; i < NBUK; i += 256) {
        int c = h[i];
        base[i] = c ? atomicAdd(&bucketCursor[i], c) : 0;
        h[i] = 0;  // reuse as intra-block offset
    }
    __syncthreads();
    for (int k = threadIdx.x; k < 4096; k += 256) {
        int e = b0 + k;
        if (e < E) {
            int d = edges[E + e];
            int b = d >> 8;
            int off = atomicAdd(&h[b], 1);
            bucketed[base[b] + off] = edges[e] | ((d & 255) << 20);
        }
    }
}

// ---------------- per-bucket counting sort -> rowStart, cnt, sortedSrc -------
__global__ __launch_bounds__(256) void bucket_sort_kernel(const int* __restrict__ bucketed,
                                                          const int* __restrict__ bucketStart,
                                                          int* __restrict__ rowStart,
                                                          int* __restrict__ cnt,
                                                          int* __restrict__ sortedSrc, int N) {
    __shared__ int h[256];
    __shared__ int pos[256];
    int b = blockIdx.x;
    int tid = threadIdx.x;
    int start = bucketStart[b], end = bucketStart[b + 1];
    h[tid] = 0;
    __syncthreads();
    for (int k = start + tid; k < end; k += 256) atomicAdd(&h[bucketed[k] >> 20], 1);
    __syncthreads();
    int v = h[tid];
    pos[tid] = v;
    __syncthreads();
    for (int off = 1; off < 256; off <<= 1) {
        int t = (tid >= off) ? pos[tid - off] : 0;
        __syncthreads();
        pos[tid] += t;
        __syncthreads();
    }
    int excl = start + pos[tid] - v;
    int node = (b << 8) + tid;
    if (node < N) {
        rowStart[node] = excl;
        cnt[node] = v;
    }
    h[tid] = excl;  // reuse as per-node cursor
    __syncthreads();
    for (int k = start + tid; k < end; k += 256) {
        int entry = bucketed[k];
        int p = atomicAdd(&h[entry >> 20], 1);
        sortedSrc[p] = entry & 0xFFFFF;
    }
}

// ---------------- register-tiled GEMM: O[:, cBase:cBase+128] = X @ Wcat^T ----
// X: [N,128]. Wcat logical [coutTotal,128] = Wa (CHALF rows) stacked on Wb.
// Block: 256 threads, tile 128 rows x 128 cols, per-thread 8x8, K chunked 32.
__global__ __launch_bounds__(256, 4) void gemm_rt_kernel(
    const float* __restrict__ X, const float* __restrict__ Wa,
    const float* __restrict__ Wb, int CHALF,
    float* __restrict__ O, int OSTRIDE, int N)
{
    __shared__ float xsT[32 * 128];  // xsT[k][r]
    __shared__ float wt[32 * 128];   // wt[k][c]

    const int tid = threadIdx.x;
    const int ct = tid & 15;         // col-thread
    const int rt = tid >> 4;         // row-thread
    const int rowBase = blockIdx.x * 128;
    const int cBase = blockIdx.y * 128;

    const int rr = tid & 127;        // staging row/col id
    const int kq0 = tid >> 7;        // staging float4-phase (0 or 1)
    const int grStage = rowBase + rr;
    const int cg = cBase + rr;
    const float* __restrict__ wsrc =
        (cg < CHALF) ? (Wa + (size_t)cg * 128) : (Wb + (size_t)(cg - CHALF) * 128);

    float a[8][8];
#pragma unroll
    for (int i = 0; i < 8; ++i)
#pragma unroll
        for (int j = 0; j < 8; ++j) a[i][j] = 0.f;

    for (int kc = 0; kc < 128; kc += 32) {
        __syncthreads();
        // stage X^T chunk: lanes map to rows (conflict-free LDS writes, bank=r%32)
#pragma unroll
        for (int kq = kq0; kq < 8; kq += 2) {
            float4 v = make_float4(0.f, 0.f, 0.f, 0.f);
            if (grStage < N)
                v = *reinterpret_cast<const float4*>(&X[(size_t)grStage * 128 + kc + kq * 4]);
            xsT[(kq * 4 + 0) * 128 + rr] = v.x;
            xsT[(kq * 4 + 1) * 128 + rr] = v.y;
            xsT[(kq * 4 + 2) * 128 + rr] = v.z;
            xsT[(kq * 4 + 3) * 128 + rr] = v.w;
        }
        // stage W^T chunk
#pragma unroll
        for (int kq = kq0; kq < 8; kq += 2) {
            float4 v = *reinterpret_cast<const float4*>(&wsrc[kc + kq * 4]);
            wt[(kq * 4 + 0) * 128 + rr] = v.x;
            wt[(kq * 4 + 1) * 128 + rr] = v.y;
            wt[(kq * 4 + 2) * 128 + rr] = v.z;
            wt[(kq * 4 + 3) * 128 + rr] = v.w;
        }
        __syncthreads();

#pragma unroll 4
        for (int k = 0; k < 32; ++k) {
            float4 x0 = *reinterpret_cast<const float4*>(&xsT[k * 128 + rt * 8]);
            float4 x1 = *reinterpret_cast<const float4*>(&xsT[k * 128 + rt * 8 + 4]);
            float4 w0 = *reinterpret_cast<const float4*>(&wt[k * 128 + ct * 8]);
            float4 w1 = *reinterpret_cast<const float4*>(&wt[k * 128 + ct * 8 + 4]);
            float xv[8] = {x0.x, x0.y, x0.z, x0.w, x1.x, x1.y, x1.z, x1.w};
            float wv[8] = {w0.x, w0.y, w0.z, w0.w, w1.x, w1.y, w1.z, w1.w};
#pragma unroll
            for (int i = 0; i < 8; ++i)
#pragma unroll
                for (int j = 0; j < 8; ++j)
                    a[i][j] = fmaf(xv[i], wv[j], a[i][j]);
        }
    }

    // epilogue: coalesced float4 stores
#pragma unroll
    for (int i = 0; i < 8; ++i) {
        int gr = rowBase + rt * 8 + i;
        if (gr < N) {
            float4 o0 = make_float4(a[i][0], a[i][1], a[i][2], a[i][3]);
            float4 o1 = make_float4(a[i][4], a[i][5], a[i][6], a[i][7]);
            float* p = &O[(size_t)gr * OSTRIDE + cBase + ct * 8];
            *reinterpret_cast<float4*>(p) = o0;
            *reinterpret_cast<float4*>(p + 4) = o1;
        }
    }
}

// ---------------- fused gather-mean + combine:
// out[n] = [relu]( (sum_{e} T[src[e]])/deg + bias + R[n] )
template <int C, bool RELU>
__global__ __launch_bounds__(256) void agg_combine_kernel(
    const float* __restrict__ T, int tStride,
    const float* __restrict__ R, int rStride,
    const int* __restrict__ sortedSrc, const int* __restrict__ rowStart,
    const int* __restrict__ cnt, const float* __restrict__ bias,
    float* __restrict__ outp, int N)
{
    constexpr int TPN = C / 2;          // threads per node (float2 each)
    constexpr int NPB = 256 / TPN;      // nodes per block
    int n = blockIdx.x * NPB + threadIdx.x / TPN;
    int c = threadIdx.x % TPN;          // float2 index
    if (n >= N) return;
    int start = rowStart[n];
    int m = cnt[n];
    const int* __restrict__ ep = sortedSrc + start;

    float ax = 0.f, ay = 0.f;
    int k = 0;
    for (; k + 4 <= m; k += 4) {
        int s0 = ep[k], s1 = ep[k + 1], s2 = ep[k + 2], s3 = ep[k + 3];
        float2 v0 = *reinterpret_cast<const float2*>(&T[(size_t)s0 * tStride + c * 2]);
        float2 v1 = *reinterpret_cast<const float2*>(&T[(size_t)s1 * tStride + c * 2]);
        float2 v2 = *reinterpret_cast<const float2*>(&T[(size_t)s2 * tStride + c * 2]);
        float2 v3 = *reinterpret_cast<const float2*>(&T[(size_t)s3 * tStride + c * 2]);
        ax += (v0.x + v1.x) + (v2.x + v3.x);
        ay += (v0.y + v1.y) + (v2.y + v3.y);
    }
    for (; k < m; ++k) {
        int s = ep[k];
        float2 v = *reinterpret_cast<const float2*>(&T[(size_t)s * tStride + c * 2]);
        ax += v.x; ay += v.y;
    }
    float inv = 1.0f / fmaxf((float)m, 1.0f);
    float2 rv = *reinterpret_cast<const float2*>(&R[(size_t)n * rStride + c * 2]);
    float bx = bias[c * 2], by = bias[c * 2 + 1];
    float ox = fmaf(ax, inv, bx) + rv.x;
    float oy = fmaf(ay, inv, by) + rv.y;
    if (RELU) { ox = fmaxf(ox, 0.f); oy = fmaxf(oy, 0.f); }
    float2 o; o.x = ox; o.y = oy;
    *reinterpret_cast<float2*>(&outp[(size_t)n * C + c * 2]) = o;
}

// ---------------- decode: wave per pair, shuffle reduce ----------------
__global__ __launch_bounds__(256) void decode_kernel(
    const float* __restrict__ z, const int* __restrict__ eli,
    const float* __restrict__ Wdec, const float* __restrict__ bdec,
    float* __restrict__ out, int P)
{
    int t = blockIdx.x * 256 + threadIdx.x;
    int p = t >> 6;
    int lane = t & 63;
    if (p >= P) return;
    int a = eli[p];
    int b = eli[P + p];
    float acc = z[(size_t)a * 64 + lane] * Wdec[lane]
              + z[(size_t)b * 64 + lane] * Wdec[64 + lane];
    for (int off = 32; off; off >>= 1) acc += __shfl_down(acc, off);
    if (lane == 0) out[p] = acc + bdec[0];
}

extern "C" void kernel_launch(void* const* d_in, const int* in_sizes, int n_in,
                              void* d_out, int out_size, void* d_ws, size_t ws_size,
                              hipStream_t stream) {
    const float* x    = (const float*)d_in[0];
    const int*   ei   = (const int*)d_in[1];
    const int*   eli  = (const int*)d_in[2];
    const float* Wl1  = (const float*)d_in[3];
    const float* bl1  = (const float*)d_in[4];
    const float* Wr1  = (const float*)d_in[5];
    const float* Wl2  = (const float*)d_in[6];
    const float* bl2  = (const float*)d_in[7];
    const float* Wr2  = (const float*)d_in[8];
    const float* Wdec = (const float*)d_in[9];
    const float* bdec = (const float*)d_in[10];
    float* out = (float*)d_out;

    const int N = NN;
    const int E = in_sizes[1] / 2;
    const int P = in_sizes[2] / 2;
    const int EB = (E + 4095) / 4096;  // edge-chunk blocks

    float* ws   = (float*)d_ws;
    float* bufH = ws;                         // [N*128] h
    float* bufO = bufH + (size_t)N * 128;     // [N*256] O1; later O2=[N*128], z at +N*128
    float* bufZ = bufO + (size_t)N * 128;     // z [N*64] (upper half of O1 region)
    int* bucketCnt    = (int*)(bufO + (size_t)N * 256); // [NBUK]
    int* bucketStart  = bucketCnt + NBUK;               // [NBUK+1]
    int* bucketCursor = bucketStart + NBUK + 1;         // [NBUK]
    int* rowStart     = bucketCursor + NBUK;            // [N]
    int* cnt          = rowStart + N;                   // [N]
    int* bucketed     = cnt + N;                        // [E]
    int* sortedSrc    = bucketed + E;                   // [E]

    // ---- build CSR by dst (radix partition + per-bucket counting sort) ----
    zero_buckets_kernel<<<1, 512, 0, stream>>>(bucketCnt);
    hist_kernel<<<EB, 256, 0, stream>>>(ei + E, bucketCnt, E);
    bucket_scan_kernel<<<1, 512, 0, stream>>>(bucketCnt, bucketStart, bucketCursor);
    partition_kernel<<<EB, 256, 0, stream>>>(ei, bucketCursor, bucketed, E);
    bucket_sort_kernel<<<NBUK, 256, 0, stream>>>(bucketed, bucketStart, rowStart, cnt, sortedSrc, N);

    // ---- layer 1: O1 = x @ [Wl1;Wr1]^T  ([N,256], t1 = cols 0:128, r1 = 128:256)
    {
        dim3 grid((N + 127) / 128, 2);
        gemm_rt_kernel<<<grid, 256, 0, stream>>>(x, Wl1, Wr1, 128, bufO, 256, N);
    }
    // h = relu(mean(t1) + bl1 + r1) -> bufH
    agg_combine_kernel<128, true><<<(N + 3) / 4, 256, 0, stream>>>(
        bufO, 256, bufO + 128, 256, sortedSrc, rowStart, cnt, bl1, bufH, N);

    // ---- layer 2: O2 = h @ [Wl2;Wr2]^T  ([N,128], t2 = cols 0:64, r2 = 64:128)
    {
        dim3 grid((N + 127) / 128, 1);
        gemm_rt_kernel<<<grid, 256, 0, stream>>>(bufH, Wl2, Wr2, 64, bufO, 128, N);
    }
    // z = mean(t2) + bl2 + r2 -> bufZ
    agg_combine_kernel<64, false><<<(N + 7) / 8, 256, 0, stream>>>(
        bufO, 128, bufO + 64, 128, sortedSrc, rowStart, cnt, bl2, bufZ, N);

    // ---- decode ----
    decode_kernel<<<(P + 3) / 4, 256, 0, stream>>>(bufZ, eli, Wdec, bdec, out, P);
}

// Round 5
// 256.562 us; speedup vs baseline: 8.3110x; 1.8031x over previous
//
#include <hip/hip_runtime.h>

#define NN 100000
#define NBUK ((NN + 255) / 256)   // 391 dst buckets of 256 nodes

typedef unsigned short u16;
typedef unsigned int u32;
typedef __attribute__((ext_vector_type(8))) short short8v;
typedef __attribute__((ext_vector_type(4))) float float4v;

__device__ __forceinline__ u32 f2bf_rne(float f) {
    u32 x = __float_as_uint(f);
    return (x + 0x7fffu + ((x >> 16) & 1u)) >> 16;
}
__device__ __forceinline__ float bf2f(u32 u) {
    return __uint_as_float(u << 16);
}

// ---------------- fp32 -> bf16 pack (float4 -> uint2 grid-stride) ------------
__global__ void f2bf_kernel(const float* __restrict__ in, u16* __restrict__ out, long n4) {
    long i = (long)blockIdx.x * blockDim.x + threadIdx.x;
    long stride = (long)gridDim.x * blockDim.x;
    for (long j = i; j < n4; j += stride) {
        float4 v = reinterpret_cast<const float4*>(in)[j];
        uint2 o;
        o.x = f2bf_rne(v.x) | (f2bf_rne(v.y) << 16);
        o.y = f2bf_rne(v.z) | (f2bf_rne(v.w) << 16);
        reinterpret_cast<uint2*>(out)[j] = o;
    }
}

// ---------------- tiny zero for bucket counters ----------------
__global__ void zero_buckets_kernel(int* __restrict__ p) {
    int i = threadIdx.x;
    if (i < NBUK) p[i] = 0;
}

// ---------------- bucket histogram (LDS pre-aggregated) ----------------
__global__ __launch_bounds__(256) void hist_kernel(const int* __restrict__ dst,
                                                   int* __restrict__ bucketCnt, int E) {
    __shared__ int h[NBUK];
    for (int i = threadIdx.x; i < NBUK; i += 256) h[i] = 0;
    __syncthreads();
    int base = blockIdx.x * 4096;
    for (int k = threadIdx.x; k < 4096; k += 256) {
        int e = base + k;
        if (e < E) atomicAdd(&h[dst[e] >> 8], 1);
    }
    __syncthreads();
    for (int i = threadIdx.x; i < NBUK; i += 256)
        if (h[i]) atomicAdd(&bucketCnt[i], h[i]);
}

// ---------------- scan bucket counts -> bucketStart[NBUK+1], init cursors ----
__global__ void bucket_scan_kernel(const int* __restrict__ bucketCnt,
                                   int* __restrict__ bucketStart,
                                   int* __restrict__ bucketCursor) {
    __shared__ int s[512];
    int tid = threadIdx.x;
    int v = (tid < NBUK) ? bucketCnt[tid] : 0;
    s[tid] = v;
    __syncthreads();
    for (int off = 1; off < 512; off <<= 1) {
        int t = (tid >= off) ? s[tid - off] : 0;
        __syncthreads();
        s[tid] += t;
        __syncthreads();
    }
    if (tid < NBUK) {
        int st = s[tid] - v;
        bucketStart[tid] = st;
        bucketCursor[tid] = st;
    }
    if (tid == NBUK - 1) bucketStart[NBUK] = s[tid];
}

// ---------------- partition edges into dst buckets (packed src|dstlow) -------
__global__ __launch_bounds__(256) void partition_kernel(const int* __restrict__ edges,
                                                        int* __restrict__ bucketCursor,
                                                        int* __restrict__ bucketed, int E) {
    __shared__ int h[NBUK];
    __shared__ int base[NBUK];
    for (int i = threadIdx.x; i < NBUK; i += 256) h[i] = 0;
    __syncthreads();
    int b0 = blockIdx.x * 4096;
    for (int k = threadIdx.x; k < 4096; k += 256) {
        int e = b0 + k;
        if (e < E) atomicAdd(&h[edges[E + e] >> 8], 1);
    }
    __syncthreads();
    for (int i = threadIdx.x; i < NBUK; i += 256) {
        int c = h[i];
        base[i] = c ? atomicAdd(&bucketCursor[i], c) : 0;
        h[i] = 0;  // reuse as intra-block offset
    }
    __syncthreads();
    for (int k = threadIdx.x; k < 4096; k += 256) {
        int e = b0 + k;
        if (e < E) {
            int d = edges[E + e];
            int b = d >> 8;
            int off = atomicAdd(&h[b], 1);
            bucketed[base[b] + off] = edges[e] | ((d & 255) << 20);
        }
    }
}

// ---------------- per-bucket counting sort -> rowStart, cnt, sortedSrc -------
__global__ __launch_bounds__(256) void bucket_sort_kernel(const int* __restrict__ bucketed,
                                                          const int* __restrict__ bucketStart,
                                                          int* __restrict__ rowStart,
                                                          int* __restrict__ cnt,
                                                          int* __restrict__ sortedSrc, int N) {
    __shared__ int h[256];
    __shared__ int pos[256];
    int b = blockIdx.x;
    int tid = threadIdx.x;
    int start = bucketStart[b], end = bucketStart[b + 1];
    h[tid] = 0;
    __syncthreads();
    for (int k = start + tid; k < end; k += 256) atomicAdd(&h[bucketed[k] >> 20], 1);
    __syncthreads();
    int v = h[tid];
    pos[tid] = v;
    __syncthreads();
    for (int off = 1; off < 256; off <<= 1) {
        int t = (tid >= off) ? pos[tid - off] : 0;
        __syncthreads();
        pos[tid] += t;
        __syncthreads();
    }
    int excl = start + pos[tid] - v;
    int node = (b << 8) + tid;
    if (node < N) {
        rowStart[node] = excl;
        cnt[node] = v;
    }
    h[tid] = excl;  // reuse as per-node cursor
    __syncthreads();
    for (int k = start + tid; k < end; k += 256) {
        int entry = bucketed[k];
        int p = atomicAdd(&h[entry >> 20], 1);
        sortedSrc[p] = entry & 0xFFFFF;
    }
}

// ---------------- MFMA GEMM: O[:, cBase:cBase+128] = Xb @ Wb^T (bf16 in, bf16 out)
// Xb [N][128] bf16, Wb [COUT][128] bf16. Block: 4 waves, tile 128x128.
// Wave w: 128 rows x cols [w*32, w*32+32). A panel XOR-swizzled in LDS.
__global__ __launch_bounds__(256, 2) void gemm_mfma_kernel(
    const u16* __restrict__ Xb, const u16* __restrict__ Wb,
    u16* __restrict__ Ob, int OSTRIDE, int N)
{
    __shared__ u16 As[128 * 128];   // 32 KB, row stride 256 B, chunks XOR-swizzled

    const int tid = threadIdx.x;
    const int w = tid >> 6;
    const int l = tid & 63;
    const int l15 = l & 15;
    const int lhi = l >> 4;          // 0..3
    const int rowBase = blockIdx.x * 128;
    const int cBase = blockIdx.y * 128;
    char* asb = reinterpret_cast<char*>(As);

    // ---- stage A panel: 2048 16B-chunks, 8 per thread, coalesced reads ----
    const short8v vz = {0, 0, 0, 0, 0, 0, 0, 0};
#pragma unroll
    for (int i = 0; i < 8; ++i) {
        int q = tid + i * 256;
        int r = q >> 4, c = q & 15;
        int gr = rowBase + r;
        short8v v = vz;
        if (gr < N) v = *reinterpret_cast<const short8v*>(&Xb[(size_t)gr * 128 + c * 8]);
        *reinterpret_cast<short8v*>(asb + r * 256 + ((c * 16) ^ ((r & 7) << 4))) = v;
    }

    // ---- preload B frags from global (W is L2-resident) ----
    // B layout: lane l -> col = l&15, k = lhi*8 + j
    short8v bfrag[2][4];
#pragma unroll
    for (int nj = 0; nj < 2; ++nj)
#pragma unroll
        for (int kk = 0; kk < 4; ++kk) {
            int c = cBase + w * 32 + nj * 16 + l15;
            bfrag[nj][kk] = *reinterpret_cast<const short8v*>(
                &Wb[(size_t)c * 128 + kk * 32 + lhi * 8]);
        }

    __syncthreads();

    float4v acc[8][2];
    const float4v az = {0.f, 0.f, 0.f, 0.f};
#pragma unroll
    for (int mi = 0; mi < 8; ++mi) { acc[mi][0] = az; acc[mi][1] = az; }

#pragma unroll
    for (int kk = 0; kk < 4; ++kk) {
#pragma unroll
        for (int mi = 0; mi < 8; ++mi) {
            int r = mi * 16 + l15;
            short8v a = *reinterpret_cast<const short8v*>(
                asb + r * 256 + ((kk * 64 + lhi * 16) ^ ((r & 7) << 4)));
            acc[mi][0] = __builtin_amdgcn_mfma_f32_16x16x32_bf16(a, bfrag[0][kk], acc[mi][0], 0, 0, 0);
            acc[mi][1] = __builtin_amdgcn_mfma_f32_16x16x32_bf16(a, bfrag[1][kk], acc[mi][1], 0, 0, 0);
        }
    }

    // ---- store O as bf16. D layout: col = l&15, row = lhi*4 + j ----
#pragma unroll
    for (int mi = 0; mi < 8; ++mi) {
#pragma unroll
        for (int nj = 0; nj < 2; ++nj) {
            int gc = cBase + w * 32 + nj * 16 + l15;
#pragma unroll
            for (int j = 0; j < 4; ++j) {
                int gr = rowBase + mi * 16 + lhi * 4 + j;
                if (gr < N) Ob[(size_t)gr * OSTRIDE + gc] = (u16)f2bf_rne(acc[mi][nj][j]);
            }
        }
    }
}

// ---------------- fused gather-mean + combine (bf16 features):
// out[n] = [relu]( mean_{e} T[src[e]] + bias + R[n] )
template <int C, bool RELU, bool OUTBF>
__global__ __launch_bounds__(256) void agg_combine_kernel(
    const u16* __restrict__ T, int tStride,
    const u16* __restrict__ R,            // same stride, column offset pre-added
    const int* __restrict__ sortedSrc, const int* __restrict__ rowStart,
    const int* __restrict__ cnt, const float* __restrict__ bias,
    float* __restrict__ outF, u16* __restrict__ outB, int N)
{
    constexpr int TPN = C / 4;          // threads per node (4 bf16 = 8 B each)
    constexpr int NPB = 256 / TPN;
    int n = blockIdx.x * NPB + threadIdx.x / TPN;
    int c = threadIdx.x % TPN;          // 4-col group
    if (n >= N) return;
    int start = rowStart[n];
    int m = cnt[n];
    const int* __restrict__ ep = sortedSrc + start;

    float a0 = 0.f, a1 = 0.f, a2 = 0.f, a3 = 0.f;
    int k = 0;
    for (; k + 4 <= m; k += 4) {
        int s0 = ep[k], s1 = ep[k + 1], s2 = ep[k + 2], s3 = ep[k + 3];
        uint2 v0 = *reinterpret_cast<const uint2*>(&T[(size_t)s0 * tStride + c * 4]);
        uint2 v1 = *reinterpret_cast<const uint2*>(&T[(size_t)s1 * tStride + c * 4]);
        uint2 v2 = *reinterpret_cast<const uint2*>(&T[(size_t)s2 * tStride + c * 4]);
        uint2 v3 = *reinterpret_cast<const uint2*>(&T[(size_t)s3 * tStride + c * 4]);
        a0 += bf2f(v0.x & 0xffffu) + bf2f(v1.x & 0xffffu) + bf2f(v2.x & 0xffffu) + bf2f(v3.x & 0xffffu);
        a1 += bf2f(v0.x >> 16) + bf2f(v1.x >> 16) + bf2f(v2.x >> 16) + bf2f(v3.x >> 16);
        a2 += bf2f(v0.y & 0xffffu) + bf2f(v1.y & 0xffffu) + bf2f(v2.y & 0xffffu) + bf2f(v3.y & 0xffffu);
        a3 += bf2f(v0.y >> 16) + bf2f(v1.y >> 16) + bf2f(v2.y >> 16) + bf2f(v3.y >> 16);
    }
    for (; k < m; ++k) {
        int s = ep[k];
        uint2 v = *reinterpret_cast<const uint2*>(&T[(size_t)s * tStride + c * 4]);
        a0 += bf2f(v.x & 0xffffu); a1 += bf2f(v.x >> 16);
        a2 += bf2f(v.y & 0xffffu); a3 += bf2f(v.y >> 16);
    }
    float inv = 1.0f / fmaxf((float)m, 1.0f);
    uint2 rv = *reinterpret_cast<const uint2*>(&R[(size_t)n * tStride + c * 4]);
    float o0 = fmaf(a0, inv, bias[c * 4 + 0]) + bf2f(rv.x & 0xffffu);
    float o1 = fmaf(a1, inv, bias[c * 4 + 1]) + bf2f(rv.x >> 16);
    float o2 = fmaf(a2, inv, bias[c * 4 + 2]) + bf2f(rv.y & 0xffffu);
    float o3 = fmaf(a3, inv, bias[c * 4 + 3]) + bf2f(rv.y >> 16);
    if (RELU) {
        o0 = fmaxf(o0, 0.f); o1 = fmaxf(o1, 0.f);
        o2 = fmaxf(o2, 0.f); o3 = fmaxf(o3, 0.f);
    }
    if (OUTBF) {
        uint2 o;
        o.x = f2bf_rne(o0) | (f2bf_rne(o1) << 16);
        o.y = f2bf_rne(o2) | (f2bf_rne(o3) << 16);
        *reinterpret_cast<uint2*>(&outB[(size_t)n * C + c * 4]) = o;
    } else {
        float4 o = make_float4(o0, o1, o2, o3);
        *reinterpret_cast<float4*>(&outF[(size_t)n * C + c * 4]) = o;
    }
}

// ---------------- decode: wave per pair, shuffle reduce ----------------
__global__ __launch_bounds__(256) void decode_kernel(
    const float* __restrict__ z, const int* __restrict__ eli,
    const float* __restrict__ Wdec, const float* __restrict__ bdec,
    float* __restrict__ out, int P)
{
    int t = blockIdx.x * 256 + threadIdx.x;
    int p = t >> 6;
    int lane = t & 63;
    if (p >= P) return;
    int a = eli[p];
    int b = eli[P + p];
    float acc = z[(size_t)a * 64 + lane] * Wdec[lane]
              + z[(size_t)b * 64 + lane] * Wdec[64 + lane];
    for (int off = 32; off; off >>= 1) acc += __shfl_down(acc, off);
    if (lane == 0) out[p] = acc + bdec[0];
}

extern "C" void kernel_launch(void* const* d_in, const int* in_sizes, int n_in,
                              void* d_out, int out_size, void* d_ws, size_t ws_size,
                              hipStream_t stream) {
    const float* x    = (const float*)d_in[0];
    const int*   ei   = (const int*)d_in[1];
    const int*   eli  = (const int*)d_in[2];
    const float* Wl1  = (const float*)d_in[3];
    const float* bl1  = (const float*)d_in[4];
    const float* Wr1  = (const float*)d_in[5];
    const float* Wl2  = (const float*)d_in[6];
    const float* bl2  = (const float*)d_in[7];
    const float* Wr2  = (const float*)d_in[8];
    const float* Wdec = (const float*)d_in[9];
    const float* bdec = (const float*)d_in[10];
    float* out = (float*)d_out;

    const int N = NN;
    const int E = in_sizes[1] / 2;
    const int P = in_sizes[2] / 2;
    const int EB = (E + 4095) / 4096;

    char* wp = (char*)d_ws;
    u16* xbf = (u16*)wp;  wp += (size_t)N * 128 * 2;
    u16* obf = (u16*)wp;  wp += (size_t)N * 256 * 2;   // O1 [N,256]; reused as O2 [N,128]
    u16* hbf = (u16*)wp;  wp += (size_t)N * 128 * 2;
    float* z = (float*)wp; wp += (size_t)N * 64 * 4;
    u16* w1bf = (u16*)wp; wp += 256 * 128 * 2;
    u16* w2bf = (u16*)wp; wp += 128 * 128 * 2;
    int* bucketCnt    = (int*)wp;
    int* bucketStart  = bucketCnt + NBUK;
    int* bucketCursor = bucketStart + NBUK + 1;
    int* rowStart     = bucketCursor + NBUK;
    int* cnt          = rowStart + N;
    int* bucketed     = cnt + N;
    int* sortedSrc    = bucketed + E;

    // ---- bf16 conversions ----
    f2bf_kernel<<<1024, 256, 0, stream>>>(x, xbf, (long)N * 128 / 4);
    f2bf_kernel<<<16, 256, 0, stream>>>(Wl1, w1bf, 128 * 128 / 4);
    f2bf_kernel<<<16, 256, 0, stream>>>(Wr1, w1bf + 128 * 128, 128 * 128 / 4);
    f2bf_kernel<<<8, 256, 0, stream>>>(Wl2, w2bf, 64 * 128 / 4);
    f2bf_kernel<<<8, 256, 0, stream>>>(Wr2, w2bf + 64 * 128, 64 * 128 / 4);

    // ---- build CSR by dst ----
    zero_buckets_kernel<<<1, 512, 0, stream>>>(bucketCnt);
    hist_kernel<<<EB, 256, 0, stream>>>(ei + E, bucketCnt, E);
    bucket_scan_kernel<<<1, 512, 0, stream>>>(bucketCnt, bucketStart, bucketCursor);
    partition_kernel<<<EB, 256, 0, stream>>>(ei, bucketCursor, bucketed, E);
    bucket_sort_kernel<<<NBUK, 256, 0, stream>>>(bucketed, bucketStart, rowStart, cnt, sortedSrc, N);

    // ---- layer 1: O1 = x @ [Wl1;Wr1]^T  (bf16, [N,256]) ----
    {
        dim3 grid((N + 127) / 128, 2);
        gemm_mfma_kernel<<<grid, 256, 0, stream>>>(xbf, w1bf, obf, 256, N);
    }
    agg_combine_kernel<128, true, true><<<(N + 7) / 8, 256, 0, stream>>>(
        obf, 256, obf + 128, sortedSrc, rowStart, cnt, bl1, nullptr, hbf, N);

    // ---- layer 2: O2 = h @ [Wl2;Wr2]^T  (bf16, [N,128]) ----
    {
        dim3 grid((N + 127) / 128, 1);
        gemm_mfma_kernel<<<grid, 256, 0, stream>>>(hbf, w2bf, obf, 128, N);
    }
    agg_combine_kernel<64, false, false><<<(N + 15) / 16, 256, 0, stream>>>(
        obf, 128, obf + 64, sortedSrc, rowStart, cnt, bl2, z, nullptr, N);

    // ---- decode ----
    decode_kernel<<<(P + 3) / 4, 256, 0, stream>>>(z, eli, Wdec, bdec, out, P);
}

// Round 6
// 255.987 us; speedup vs baseline: 8.3297x; 1.0022x over previous
//
#include <hip/hip_runtime.h>

#define NN 100000
#define NBUK ((NN + 255) / 256)   // 391 dst buckets of 256 nodes

typedef unsigned short u16;
typedef unsigned int u32;
typedef __attribute__((ext_vector_type(8))) short short8v;
typedef __attribute__((ext_vector_type(4))) float float4v;

__device__ __forceinline__ u32 f2bf_rne(float f) {
    u32 x = __float_as_uint(f);
    return (x + 0x7fffu + ((x >> 16) & 1u)) >> 16;
}
__device__ __forceinline__ float bf2f(u32 u) {
    return __uint_as_float(u << 16);
}
__device__ __forceinline__ uint4 pack8u(const float4& a, const float4& b) {
    uint4 u;
    u.x = f2bf_rne(a.x) | (f2bf_rne(a.y) << 16);
    u.y = f2bf_rne(a.z) | (f2bf_rne(a.w) << 16);
    u.z = f2bf_rne(b.x) | (f2bf_rne(b.y) << 16);
    u.w = f2bf_rne(b.z) | (f2bf_rne(b.w) << 16);
    return u;
}

// ---------------- tiny zero for bucket counters ----------------
__global__ void zero_buckets_kernel(int* __restrict__ p) {
    int i = threadIdx.x;
    if (i < NBUK) p[i] = 0;
}

// ---------------- bucket histogram (LDS pre-aggregated) ----------------
__global__ __launch_bounds__(256) void hist_kernel(const int* __restrict__ dst,
                                                   int* __restrict__ bucketCnt, int E) {
    __shared__ int h[NBUK];
    for (int i = threadIdx.x; i < NBUK; i += 256) h[i] = 0;
    __syncthreads();
    int base = blockIdx.x * 4096;
    for (int k = threadIdx.x; k < 4096; k += 256) {
        int e = base + k;
        if (e < E) atomicAdd(&h[dst[e] >> 8], 1);
    }
    __syncthreads();
    for (int i = threadIdx.x; i < NBUK; i += 256)
        if (h[i]) atomicAdd(&bucketCnt[i], h[i]);
}

// ---------------- scan bucket counts -> bucketStart[NBUK+1], init cursors ----
__global__ void bucket_scan_kernel(const int* __restrict__ bucketCnt,
                                   int* __restrict__ bucketStart,
                                   int* __restrict__ bucketCursor) {
    __shared__ int s[512];
    int tid = threadIdx.x;
    int v = (tid < NBUK) ? bucketCnt[tid] : 0;
    s[tid] = v;
    __syncthreads();
    for (int off = 1; off < 512; off <<= 1) {
        int t = (tid >= off) ? s[tid - off] : 0;
        __syncthreads();
        s[tid] += t;
        __syncthreads();
    }
    if (tid < NBUK) {
        int st = s[tid] - v;
        bucketStart[tid] = st;
        bucketCursor[tid] = st;
    }
    if (tid == NBUK - 1) bucketStart[NBUK] = s[tid];
}

// ---------------- partition edges into dst buckets (packed src|dstlow) -------
__global__ __launch_bounds__(256) void partition_kernel(const int* __restrict__ edges,
                                                        int* __restrict__ bucketCursor,
                                                        int* __restrict__ bucketed, int E) {
    __shared__ int h[NBUK];
    __shared__ int base[NBUK];
    for (int i = threadIdx.x; i < NBUK; i += 256) h[i] = 0;
    __syncthreads();
    int b0 = blockIdx.x * 4096;
    for (int k = threadIdx.x; k < 4096; k += 256) {
        int e = b0 + k;
        if (e < E) atomicAdd(&h[edges[E + e] >> 8], 1);
    }
    __syncthreads();
    for (int i = threadIdx.x; i < NBUK; i += 256) {
        int c = h[i];
        base[i] = c ? atomicAdd(&bucketCursor[i], c) : 0;
        h[i] = 0;  // reuse as intra-block offset
    }
    __syncthreads();
    for (int k = threadIdx.x; k < 4096; k += 256) {
        int e = b0 + k;
        if (e < E) {
            int d = edges[E + e];
            int b = d >> 8;
            int off = atomicAdd(&h[b], 1);
            bucketed[base[b] + off] = edges[e] | ((d & 255) << 20);
        }
    }
}

// ---------------- per-bucket counting sort -> rowStart, cnt, sortedSrc -------
__global__ __launch_bounds__(256) void bucket_sort_kernel(const int* __restrict__ bucketed,
                                                          const int* __restrict__ bucketStart,
                                                          int* __restrict__ rowStart,
                                                          int* __restrict__ cnt,
                                                          int* __restrict__ sortedSrc, int N) {
    __shared__ int h[256];
    __shared__ int pos[256];
    int b = blockIdx.x;
    int tid = threadIdx.x;
    int start = bucketStart[b], end = bucketStart[b + 1];
    h[tid] = 0;
    __syncthreads();
    for (int k = start + tid; k < end; k += 256) atomicAdd(&h[bucketed[k] >> 20], 1);
    __syncthreads();
    int v = h[tid];
    pos[tid] = v;
    __syncthreads();
    for (int off = 1; off < 256; off <<= 1) {
        int t = (tid >= off) ? pos[tid - off] : 0;
        __syncthreads();
        pos[tid] += t;
        __syncthreads();
    }
    int excl = start + pos[tid] - v;
    int node = (b << 8) + tid;
    if (node < N) {
        rowStart[node] = excl;
        cnt[node] = v;
    }
    h[tid] = excl;  // reuse as per-node cursor
    __syncthreads();
    for (int k = start + tid; k < end; k += 256) {
        int entry = bucketed[k];
        int p = atomicAdd(&h[entry >> 20], 1);
        sortedSrc[p] = entry & 0xFFFFF;
    }
}

// ---------------- MFMA GEMM: O[:, cBase:cBase+128] = X @ [Wa;Wb]^T -----------
// X: [N,128] (fp32 if XF32 else bf16). Wa/Wb fp32 [CHALF / rest][128],
// converted to bf16 inline. Block: 4 waves, tile 128x128. O bf16.
template <bool XF32>
__global__ __launch_bounds__(256, 2) void gemm_mfma_kernel(
    const void* __restrict__ Xv, const float* __restrict__ Wa,
    const float* __restrict__ Wb, int CHALF,
    u16* __restrict__ Ob, int OSTRIDE, int N)
{
    __shared__ u16 As[128 * 128];   // 32 KB, row stride 256 B, chunks XOR-swizzled

    const int tid = threadIdx.x;
    const int w = tid >> 6;
    const int l = tid & 63;
    const int l15 = l & 15;
    const int lhi = l >> 4;          // 0..3
    const int rowBase = blockIdx.x * 128;
    const int cBase = blockIdx.y * 128;
    char* asb = reinterpret_cast<char*>(As);

    // ---- stage A panel: 2048 16B-chunks (8 bf16), 8 per thread ----
#pragma unroll
    for (int i = 0; i < 8; ++i) {
        int q = tid + i * 256;
        int r = q >> 4, c = q & 15;
        int gr = rowBase + r;
        uint4 pk = make_uint4(0u, 0u, 0u, 0u);
        if (gr < N) {
            if (XF32) {
                const float* xf = (const float*)Xv + (size_t)gr * 128 + c * 8;
                float4 f0 = *reinterpret_cast<const float4*>(xf);
                float4 f1 = *reinterpret_cast<const float4*>(xf + 4);
                pk = pack8u(f0, f1);
            } else {
                pk = *reinterpret_cast<const uint4*>((const u16*)Xv + (size_t)gr * 128 + c * 8);
            }
        }
        *reinterpret_cast<uint4*>(asb + r * 256 + ((c * 16) ^ ((r & 7) << 4))) = pk;
    }

    // ---- preload B frags from fp32 W (L2-resident), convert inline ----
    // B layout: lane l -> col = l&15, k = lhi*8 + j
    short8v bfrag[2][4];
#pragma unroll
    for (int nj = 0; nj < 2; ++nj) {
        int c = cBase + w * 32 + nj * 16 + l15;
        const float* wr = (c < CHALF) ? (Wa + (size_t)c * 128)
                                      : (Wb + (size_t)(c - CHALF) * 128);
#pragma unroll
        for (int kk = 0; kk < 4; ++kk) {
            float4 f0 = *reinterpret_cast<const float4*>(wr + kk * 32 + lhi * 8);
            float4 f1 = *reinterpret_cast<const float4*>(wr + kk * 32 + lhi * 8 + 4);
            uint4 pk = pack8u(f0, f1);
            union { uint4 u; short8v s; } cv; cv.u = pk;
            bfrag[nj][kk] = cv.s;
        }
    }

    __syncthreads();

    float4v acc[8][2];
    const float4v az = {0.f, 0.f, 0.f, 0.f};
#pragma unroll
    for (int mi = 0; mi < 8; ++mi) { acc[mi][0] = az; acc[mi][1] = az; }

#pragma unroll
    for (int kk = 0; kk < 4; ++kk) {
#pragma unroll
        for (int mi = 0; mi < 8; ++mi) {
            int r = mi * 16 + l15;
            short8v a = *reinterpret_cast<const short8v*>(
                asb + r * 256 + ((kk * 64 + lhi * 16) ^ ((r & 7) << 4)));
            acc[mi][0] = __builtin_amdgcn_mfma_f32_16x16x32_bf16(a, bfrag[0][kk], acc[mi][0], 0, 0, 0);
            acc[mi][1] = __builtin_amdgcn_mfma_f32_16x16x32_bf16(a, bfrag[1][kk], acc[mi][1], 0, 0, 0);
        }
    }

    // ---- store O as bf16. D layout: col = l&15, row = lhi*4 + j ----
#pragma unroll
    for (int mi = 0; mi < 8; ++mi) {
#pragma unroll
        for (int nj = 0; nj < 2; ++nj) {
            int gc = cBase + w * 32 + nj * 16 + l15;
#pragma unroll
            for (int j = 0; j < 4; ++j) {
                int gr = rowBase + mi * 16 + lhi * 4 + j;
                if (gr < N) Ob[(size_t)gr * OSTRIDE + gc] = (u16)f2bf_rne(acc[mi][nj][j]);
            }
        }
    }
}

// ---------------- fused gather-mean + combine (bf16 features, uint4 lanes):
// out[n] = [relu]( mean_{e} T[src[e]] + bias + R[n] )
template <int C, bool RELU, bool OUTBF>
__global__ __launch_bounds__(256) void agg_combine_kernel(
    const u16* __restrict__ T, int tStride,
    const u16* __restrict__ R,            // same stride, column offset pre-added
    const int* __restrict__ sortedSrc, const int* __restrict__ rowStart,
    const int* __restrict__ cnt, const float* __restrict__ bias,
    float* __restrict__ outF, u16* __restrict__ outB, int N)
{
    constexpr int TPN = C / 8;          // threads per node (8 bf16 = 16 B each)
    constexpr int NPB = 256 / TPN;
    int n = blockIdx.x * NPB + threadIdx.x / TPN;
    int c = threadIdx.x % TPN;          // 8-col group
    if (n >= N) return;
    int start = rowStart[n];
    int m = cnt[n];
    const int* __restrict__ ep = sortedSrc + start;
    const u16* __restrict__ tp = T + c * 8;

    float a0 = 0.f, a1 = 0.f, a2 = 0.f, a3 = 0.f;
    float a4 = 0.f, a5 = 0.f, a6 = 0.f, a7 = 0.f;
    int k = 0;
    for (; k + 4 <= m; k += 4) {
        int s0 = ep[k], s1 = ep[k + 1], s2 = ep[k + 2], s3 = ep[k + 3];
        uint4 v0 = *reinterpret_cast<const uint4*>(&tp[(size_t)s0 * tStride]);
        uint4 v1 = *reinterpret_cast<const uint4*>(&tp[(size_t)s1 * tStride]);
        uint4 v2 = *reinterpret_cast<const uint4*>(&tp[(size_t)s2 * tStride]);
        uint4 v3 = *reinterpret_cast<const uint4*>(&tp[(size_t)s3 * tStride]);
        a0 += bf2f(v0.x & 0xffffu) + bf2f(v1.x & 0xffffu) + bf2f(v2.x & 0xffffu) + bf2f(v3.x & 0xffffu);
        a1 += bf2f(v0.x >> 16) + bf2f(v1.x >> 16) + bf2f(v2.x >> 16) + bf2f(v3.x >> 16);
        a2 += bf2f(v0.y & 0xffffu) + bf2f(v1.y & 0xffffu) + bf2f(v2.y & 0xffffu) + bf2f(v3.y & 0xffffu);
        a3 += bf2f(v0.y >> 16) + bf2f(v1.y >> 16) + bf2f(v2.y >> 16) + bf2f(v3.y >> 16);
        a4 += bf2f(v0.z & 0xffffu) + bf2f(v1.z & 0xffffu) + bf2f(v2.z & 0xffffu) + bf2f(v3.z & 0xffffu);
        a5 += bf2f(v0.z >> 16) + bf2f(v1.z >> 16) + bf2f(v2.z >> 16) + bf2f(v3.z >> 16);
        a6 += bf2f(v0.w & 0xffffu) + bf2f(v1.w & 0xffffu) + bf2f(v2.w & 0xffffu) + bf2f(v3.w & 0xffffu);
        a7 += bf2f(v0.w >> 16) + bf2f(v1.w >> 16) + bf2f(v2.w >> 16) + bf2f(v3.w >> 16);
    }
    for (; k < m; ++k) {
        uint4 v = *reinterpret_cast<const uint4*>(&tp[(size_t)ep[k] * tStride]);
        a0 += bf2f(v.x & 0xffffu); a1 += bf2f(v.x >> 16);
        a2 += bf2f(v.y & 0xffffu); a3 += bf2f(v.y >> 16);
        a4 += bf2f(v.z & 0xffffu); a5 += bf2f(v.z >> 16);
        a6 += bf2f(v.w & 0xffffu); a7 += bf2f(v.w >> 16);
    }
    float inv = 1.0f / fmaxf((float)m, 1.0f);
    uint4 rv = *reinterpret_cast<const uint4*>(&R[(size_t)n * tStride + c * 8]);
    float o0 = fmaf(a0, inv, bias[c * 8 + 0]) + bf2f(rv.x & 0xffffu);
    float o1 = fmaf(a1, inv, bias[c * 8 + 1]) + bf2f(rv.x >> 16);
    float o2 = fmaf(a2, inv, bias[c * 8 + 2]) + bf2f(rv.y & 0xffffu);
    float o3 = fmaf(a3, inv, bias[c * 8 + 3]) + bf2f(rv.y >> 16);
    float o4 = fmaf(a4, inv, bias[c * 8 + 4]) + bf2f(rv.z & 0xffffu);
    float o5 = fmaf(a5, inv, bias[c * 8 + 5]) + bf2f(rv.z >> 16);
    float o6 = fmaf(a6, inv, bias[c * 8 + 6]) + bf2f(rv.w & 0xffffu);
    float o7 = fmaf(a7, inv, bias[c * 8 + 7]) + bf2f(rv.w >> 16);
    if (RELU) {
        o0 = fmaxf(o0, 0.f); o1 = fmaxf(o1, 0.f);
        o2 = fmaxf(o2, 0.f); o3 = fmaxf(o3, 0.f);
        o4 = fmaxf(o4, 0.f); o5 = fmaxf(o5, 0.f);
        o6 = fmaxf(o6, 0.f); o7 = fmaxf(o7, 0.f);
    }
    if (OUTBF) {
        uint4 o;
        o.x = f2bf_rne(o0) | (f2bf_rne(o1) << 16);
        o.y = f2bf_rne(o2) | (f2bf_rne(o3) << 16);
        o.z = f2bf_rne(o4) | (f2bf_rne(o5) << 16);
        o.w = f2bf_rne(o6) | (f2bf_rne(o7) << 16);
        *reinterpret_cast<uint4*>(&outB[(size_t)n * C + c * 8]) = o;
    } else {
        float4 lo = make_float4(o0, o1, o2, o3);
        float4 hi = make_float4(o4, o5, o6, o7);
        float* p = &outF[(size_t)n * C + c * 8];
        *reinterpret_cast<float4*>(p) = lo;
        *reinterpret_cast<float4*>(p + 4) = hi;
    }
}

// ---------------- decode: wave per pair, shuffle reduce ----------------
__global__ __launch_bounds__(256) void decode_kernel(
    const float* __restrict__ z, const int* __restrict__ eli,
    const float* __restrict__ Wdec, const float* __restrict__ bdec,
    float* __restrict__ out, int P)
{
    int t = blockIdx.x * 256 + threadIdx.x;
    int p = t >> 6;
    int lane = t & 63;
    if (p >= P) return;
    int a = eli[p];
    int b = eli[P + p];
    float acc = z[(size_t)a * 64 + lane] * Wdec[lane]
              + z[(size_t)b * 64 + lane] * Wdec[64 + lane];
    for (int off = 32; off; off >>= 1) acc += __shfl_down(acc, off);
    if (lane == 0) out[p] = acc + bdec[0];
}

extern "C" void kernel_launch(void* const* d_in, const int* in_sizes, int n_in,
                              void* d_out, int out_size, void* d_ws, size_t ws_size,
                              hipStream_t stream) {
    const float* x    = (const float*)d_in[0];
    const int*   ei   = (const int*)d_in[1];
    const int*   eli  = (const int*)d_in[2];
    const float* Wl1  = (const float*)d_in[3];
    const float* bl1  = (const float*)d_in[4];
    const float* Wr1  = (const float*)d_in[5];
    const float* Wl2  = (const float*)d_in[6];
    const float* bl2  = (const float*)d_in[7];
    const float* Wr2  = (const float*)d_in[8];
    const float* Wdec = (const float*)d_in[9];
    const float* bdec = (const float*)d_in[10];
    float* out = (float*)d_out;

    const int N = NN;
    const int E = in_sizes[1] / 2;
    const int P = in_sizes[2] / 2;
    const int EB = (E + 4095) / 4096;

    char* wp = (char*)d_ws;
    u16* obf = (u16*)wp;  wp += (size_t)N * 256 * 2;   // O1 [N,256]; reused as O2 [N,128]
    u16* hbf = (u16*)wp;  wp += (size_t)N * 128 * 2;
    float* z = (float*)wp; wp += (size_t)N * 64 * 4;
    int* bucketCnt    = (int*)wp;
    int* bucketStart  = bucketCnt + NBUK;
    int* bucketCursor = bucketStart + NBUK + 1;
    int* rowStart     = bucketCursor + NBUK;
    int* cnt          = rowStart + N;
    int* bucketed     = cnt + N;
    int* sortedSrc    = bucketed + E;

    // ---- build CSR by dst ----
    zero_buckets_kernel<<<1, 512, 0, stream>>>(bucketCnt);
    hist_kernel<<<EB, 256, 0, stream>>>(ei + E, bucketCnt, E);
    bucket_scan_kernel<<<1, 512, 0, stream>>>(bucketCnt, bucketStart, bucketCursor);
    partition_kernel<<<EB, 256, 0, stream>>>(ei, bucketCursor, bucketed, E);
    bucket_sort_kernel<<<NBUK, 256, 0, stream>>>(bucketed, bucketStart, rowStart, cnt, sortedSrc, N);

    // ---- layer 1: O1 = x @ [Wl1;Wr1]^T  (bf16, [N,256]) ----
    {
        dim3 grid((N + 127) / 128, 2);
        gemm_mfma_kernel<true><<<grid, 256, 0, stream>>>(x, Wl1, Wr1, 128, obf, 256, N);
    }
    agg_combine_kernel<128, true, true><<<(N + 15) / 16, 256, 0, stream>>>(
        obf, 256, obf + 128, sortedSrc, rowStart, cnt, bl1, nullptr, hbf, N);

    // ---- layer 2: O2 = h @ [Wl2;Wr2]^T  (bf16, [N,128]) ----
    {
        dim3 grid((N + 127) / 128, 1);
        gemm_mfma_kernel<false><<<grid, 256, 0, stream>>>(hbf, Wl2, Wr2, 64, obf, 128, N);
    }
    agg_combine_kernel<64, false, false><<<(N + 31) / 32, 256, 0, stream>>>(
        obf, 128, obf + 64, sortedSrc, rowStart, cnt, bl2, z, nullptr, N);

    // ---- decode ----
    decode_kernel<<<(P + 3) / 4, 256, 0, stream>>>(z, eli, Wdec, bdec, out, P);
}